// Round 1
// 1274.409 us; speedup vs baseline: 1.0048x; 1.0048x over previous
//
#include <hip/hip_runtime.h>
#include <hip/hip_bf16.h>
#include <math.h>

// TransformerBlock3D: B=8, C=128, S=32 (N=32768), HEADS=8 (dim_head=16), MLP=512
// Round 5: k_mlp barrier diet. Counters showed k_mlp latency-bound (MfmaUtil 5.5%,
// VALUBusy 13%, HBM 8%, occ 22%): 9 barriers/block with only 2 blocks/CU.
// hT is wave-private by rows (writes nr=wave*32+n2*16+r, reads nr0=wave*32+r,
// nr1=nr0+16 -> same 32-row band), and the epilogue's xT residual reads are
// also own-rows. So both in-loop __syncthreads are unnecessary; only the
// post-staging barrier (column-split staging vs all-column GEMM1 reads) stays.
// Waves now run the stage->GEMM1->gelu->GEMM2 pipeline independently.
// Math: G=XX^T, attn=softmax(0.25*WqGWk^T), Mb=P.blockdiag(attn).Wv (bf16),
//       x1pre = Mb x + proj_b + x; x1 = LN1(x1pre); x2pre = x1 + b2 + W2 gelu(W1 x1 + b1).

#define N_SP 32768
typedef __hip_bfloat16 bf16;
static const size_t DS = (size_t)128 * N_SP;

typedef __attribute__((ext_vector_type(8))) short s8b;
typedef __attribute__((ext_vector_type(4))) float f4;

__device__ __forceinline__ ushort f2b(float f) {
    __hip_bfloat16 h = __float2bfloat16(f);
    return *reinterpret_cast<ushort*>(&h);
}
__device__ __forceinline__ float b2f(ushort u) {
    unsigned v = ((unsigned)u) << 16;
    float f;
    __builtin_memcpy(&f, &v, 4);
    return f;
}
__device__ __forceinline__ float gelu_f(float h) {
    float u = 1.5957691216057308f * h * fmaf(0.044715f, h * h, 1.0f);
    float e = __expf(u);
    return h * (1.0f - __builtin_amdgcn_rcpf(e + 1.0f));
}
// swizzled index for 128-col bf16 LDS tiles (c0 multiple of 8)
__device__ __forceinline__ int swz8(int n, int c0) {
    return n * 128 + (c0 ^ ((n & 15) << 3));
}
// swizzled index, c0 multiple of 4
__device__ __forceinline__ int swz4(int n, int c0) {
    return n * 128 + (((c0 & 0x78) ^ ((n & 15) << 3)) | (c0 & 4));
}

// ---------- tiny transpose ----------
__global__ __launch_bounds__(256) void k_transpose(const float* __restrict__ in,
                                                   float* __restrict__ out,
                                                   int R, int Ccols) {
    int idx = blockIdx.x * 256 + threadIdx.x;
    if (idx >= R * Ccols) return;
    int r = idx / Ccols, c = idx % Ccols;
    out[c * R + r] = in[idx];
}

// ---------- fp32 -> bf16 ----------
__global__ __launch_bounds__(256) void k_cvt(const float* __restrict__ in,
                                             ushort* __restrict__ out, int n) {
    int i = blockIdx.x * 256 + threadIdx.x;
    if (i < n) out[i] = f2b(in[i]);
}

// ---------- covariance partials via MFMA: Gpart[b*64+kb] = X Xs^T over 512 n ----------
__global__ __launch_bounds__(256, 3) void k_cov(const float* __restrict__ x,
                                                float* __restrict__ Gpart) {
    __shared__ ushort xs[128 * 136];   // [c][n_local], pad 136
    const int kb = blockIdx.x, b = blockIdx.y;
    const int t = threadIdx.x;
    const int wave = t >> 6, lane = t & 63, q = lane >> 4, r = lane & 15;
    f4 acc[8][2];
#pragma unroll
    for (int m = 0; m < 8; ++m) { acc[m][0] = (f4){0,0,0,0}; acc[m][1] = (f4){0,0,0,0}; }
    for (int ch = 0; ch < 4; ++ch) {
        const int nbase = kb * 512 + ch * 128;
        __syncthreads();
        {
            const int nn = t & 127, cg = t >> 7;
            const float* xp = x + (size_t)b * DS + nbase + nn;
#pragma unroll
            for (int cc = 0; cc < 64; ++cc) {
                int c = cg * 64 + cc;
                xs[c * 136 + nn] = f2b(xp[(size_t)c * N_SP]);
            }
        }
        __syncthreads();
#pragma unroll
        for (int kk = 0; kk < 4; ++kk) {
            const int c0 = kk * 32 + q * 8;
            s8b bj0 = *(const s8b*)&xs[(wave * 32 + r) * 136 + c0];
            s8b bj1 = *(const s8b*)&xs[(wave * 32 + 16 + r) * 136 + c0];
#pragma unroll
            for (int m = 0; m < 8; ++m) {
                s8b a = *(const s8b*)&xs[(m * 16 + r) * 136 + c0];
                acc[m][0] = __builtin_amdgcn_mfma_f32_16x16x32_bf16(a, bj0, acc[m][0], 0, 0, 0);
                acc[m][1] = __builtin_amdgcn_mfma_f32_16x16x32_bf16(a, bj1, acc[m][1], 0, 0, 0);
            }
        }
    }
    float* gp = Gpart + ((size_t)b * 64 + kb) * 16384;
#pragma unroll
    for (int n2 = 0; n2 < 2; ++n2)
#pragma unroll
        for (int m = 0; m < 8; ++m)
#pragma unroll
            for (int rg = 0; rg < 4; ++rg) {
                int i = m * 16 + q * 4 + rg;
                int j = wave * 32 + n2 * 16 + r;
                gp[i * 128 + j] = acc[m][n2][rg];
            }
}

__global__ __launch_bounds__(256) void k_greduce(const float* __restrict__ Gpart,
                                                 float* __restrict__ G) {
    int tid = blockIdx.x * 256 + threadIdx.x;
    int b = tid >> 14, ij = tid & 16383;
    float s = 0.f;
    for (int kb = 0; kb < 64; ++kb)
        s += Gpart[((size_t)b * 64 + kb) * 16384 + ij];
    G[tid] = s;
}

// ---------- gram + softmax ----------
__global__ __launch_bounds__(256) void k_gram_small(const float* __restrict__ G,
                                                    const float* __restrict__ qkv_w,
                                                    float* __restrict__ attn) {
    __shared__ float t1[16 * 132];
    __shared__ float sg[16 * 16];
    const int bh = blockIdx.x;
    const int b = bh >> 3, h = bh & 7;
    const int t = threadIdx.x;
    {
        const int i = t >> 4, c20 = (t & 15) * 8;
        const float* wq = qkv_w + (size_t)(h * 16 + i) * 128;
        const float* Gb = G + (size_t)b * 16384;
        float a[8];
#pragma unroll
        for (int k = 0; k < 8; ++k) a[k] = 0.f;
        for (int c = 0; c < 128; ++c) {
            float w = wq[c];
            const float* grow = Gb + c * 128 + c20;
#pragma unroll
            for (int k = 0; k < 8; ++k) a[k] = fmaf(w, grow[k], a[k]);
        }
#pragma unroll
        for (int k = 0; k < 8; ++k) t1[i * 132 + c20 + k] = a[k];
    }
    __syncthreads();
    {
        const int i = t >> 4, j = t & 15;
        const float* wk = qkv_w + (size_t)(128 + h * 16 + j) * 128;
        float s = 0.f;
        for (int c2 = 0; c2 < 128; ++c2) s = fmaf(t1[i * 132 + c2], wk[c2], s);
        sg[i * 16 + j] = s * 0.25f;
    }
    __syncthreads();
    if (t < 16) {
        float mx = -1e30f;
#pragma unroll
        for (int j = 0; j < 16; ++j) mx = fmaxf(mx, sg[t * 16 + j]);
        float e[16], sum = 0.f;
#pragma unroll
        for (int j = 0; j < 16; ++j) { e[j] = expf(sg[t * 16 + j] - mx); sum += e[j]; }
        float inv = 1.0f / sum;
#pragma unroll
        for (int j = 0; j < 16; ++j)
            attn[((size_t)bh * 16 + t) * 16 + j] = e[j] * inv;
    }
}

// ---------- fold: Mbb[b][o][c] = bf16( (P . blockdiag(attn) . Wv)[o][c] ) ----------
__global__ __launch_bounds__(256, 2) void k_mfold(const float* __restrict__ attn,
                                                  const float* __restrict__ qkv_w,
                                                  const float* __restrict__ PT,
                                                  ushort* __restrict__ Mbb) {
    __shared__ float t2[128 * 128];
    const int b = blockIdx.x, t = threadIdx.x;
    {
        const int hi = t >> 1, c0 = (t & 1) * 64;
        const int h = hi >> 4;
        const float* at = attn + ((size_t)b * 128 + hi) * 16;
        float a[16];
#pragma unroll
        for (int j = 0; j < 16; ++j) a[j] = at[j];
        float sc[64];
#pragma unroll
        for (int c = 0; c < 64; ++c) sc[c] = 0.f;
        for (int j = 0; j < 16; ++j) {
            const float* wv = qkv_w + (size_t)(256 + h * 16 + j) * 128 + c0;
            float aj = a[j];
#pragma unroll
            for (int c = 0; c < 64; ++c) sc[c] = fmaf(aj, wv[c], sc[c]);
        }
#pragma unroll
        for (int c = 0; c < 64; ++c) t2[hi * 128 + c0 + c] = sc[c];
    }
    __syncthreads();
    const int c = t & 127, half = t >> 7;
    float acc[128];
#pragma unroll
    for (int o = 0; o < 128; ++o) acc[o] = 0.f;
    for (int ci = half * 64; ci < half * 64 + 64; ++ci) {
        float s = t2[ci * 128 + c];
        const float* pt = PT + ci * 128;
#pragma unroll
        for (int o = 0; o < 128; ++o) acc[o] = fmaf(pt[o], s, acc[o]);
    }
    __syncthreads();
    if (half) {
#pragma unroll
        for (int o = 0; o < 128; ++o) t2[c * 128 + o] = acc[o];
    }
    __syncthreads();
    if (!half) {
        ushort* m = Mbb + (size_t)b * 16384;
#pragma unroll
        for (int o = 0; o < 128; ++o)
            m[(size_t)o * 128 + c] = f2b(acc[o] + t2[c * 128 + o]);
    }
}

// ---------- attnproj: x1pre = Mb x + proj_b + x, LN1 stats. 128-col tile ----------
__global__ __launch_bounds__(256, 3) void k_attnproj(const float* __restrict__ x,
                                                     const ushort* __restrict__ Mbb,
                                                     const float* __restrict__ proj_b,
                                                     float* __restrict__ xout,
                                                     float* __restrict__ st) {
    __shared__ ushort xT[128 * 136];   // [n][c] bf16
    const int b = blockIdx.y;
    const int n0 = blockIdx.x * 128;
    const int t = threadIdx.x;
    {
        const int nn = t & 127, cg = t >> 7;
        const float* xp = x + (size_t)b * DS + n0 + nn;
#pragma unroll
        for (int g = 0; g < 16; ++g) {
            int c0 = cg * 64 + g * 4;
            ushort4 pk;
            pk.x = f2b(xp[(size_t)(c0 + 0) * N_SP]);
            pk.y = f2b(xp[(size_t)(c0 + 1) * N_SP]);
            pk.z = f2b(xp[(size_t)(c0 + 2) * N_SP]);
            pk.w = f2b(xp[(size_t)(c0 + 3) * N_SP]);
            *(ushort4*)&xT[nn * 136 + c0] = pk;
        }
    }
    __syncthreads();
    const int wave = t >> 6, lane = t & 63, q = lane >> 4, r = lane & 15;
    const ushort* mb = Mbb + (size_t)b * 16384;
    f4 acc[8][2];
#pragma unroll
    for (int m = 0; m < 8; ++m) { acc[m][0] = (f4){0,0,0,0}; acc[m][1] = (f4){0,0,0,0}; }
    const int nr0 = wave * 32 + r, nr1 = nr0 + 16;
#pragma unroll
    for (int kk = 0; kk < 4; ++kk) {
        const int c0 = kk * 32 + q * 8;
        s8b b0 = *(const s8b*)&xT[nr0 * 136 + c0];
        s8b b1 = *(const s8b*)&xT[nr1 * 136 + c0];
#pragma unroll
        for (int m = 0; m < 8; ++m) {
            s8b a = *(const s8b*)(mb + (size_t)(m * 16 + r) * 128 + c0);
            acc[m][0] = __builtin_amdgcn_mfma_f32_16x16x32_bf16(a, b0, acc[m][0], 0, 0, 0);
            acc[m][1] = __builtin_amdgcn_mfma_f32_16x16x32_bf16(a, b1, acc[m][1], 0, 0, 0);
        }
    }
    float s = 0.f, sq = 0.f;
#pragma unroll
    for (int n2 = 0; n2 < 2; ++n2) {
        const int nrl = wave * 32 + n2 * 16 + r;
        float* op = xout + (size_t)b * DS + n0 + nrl;
#pragma unroll
        for (int m = 0; m < 8; ++m) {
            const int o0 = m * 16 + q * 4;
            ushort4 xr = *(const ushort4*)&xT[nrl * 136 + o0];
            float v0 = acc[m][n2][0] + proj_b[o0 + 0] + b2f(xr.x);
            float v1 = acc[m][n2][1] + proj_b[o0 + 1] + b2f(xr.y);
            float v2 = acc[m][n2][2] + proj_b[o0 + 2] + b2f(xr.z);
            float v3 = acc[m][n2][3] + proj_b[o0 + 3] + b2f(xr.w);
            op[(size_t)(o0 + 0) * N_SP] = v0;
            op[(size_t)(o0 + 1) * N_SP] = v1;
            op[(size_t)(o0 + 2) * N_SP] = v2;
            op[(size_t)(o0 + 3) * N_SP] = v3;
            s += (v0 + v1) + (v2 + v3);
            sq = fmaf(v0, v0, sq); sq = fmaf(v1, v1, sq);
            sq = fmaf(v2, v2, sq); sq = fmaf(v3, v3, sq);
        }
    }
#pragma unroll
    for (int off = 32; off > 0; off >>= 1) {
        s += __shfl_down(s, off, 64);
        sq += __shfl_down(sq, off, 64);
    }
    if (lane == 0) {
        atomicAdd(&st[0 + b], s);
        atomicAdd(&st[8 + b], sq);
    }
}

__global__ void k_finalize(float* st, int off) {
    int b = threadIdx.x;
    if (b < 8) {
        const float invn = 1.0f / 4194304.0f;
        float mu = st[off + b] * invn;
        float var = st[off + 8 + b] * invn - mu * mu;
        st[off + 16 + b] = mu;
        st[off + 24 + b] = rsqrtf(var + 1e-5f);
    }
}

__global__ __launch_bounds__(256) void k_lnapply(const float* __restrict__ in,
                                                 const float* __restrict__ lnw,
                                                 const float* __restrict__ lnb,
                                                 const float* __restrict__ st, int off,
                                                 float* __restrict__ out) {
    size_t i4 = (size_t)blockIdx.x * 256 + threadIdx.x;
    int b = (int)(i4 >> 20);
    size_t cn = i4 * 4 - (size_t)b * 4194304;
    float mu = st[off + 16 + b], rs = st[off + 24 + b];
    const float4 xv = *(const float4*)(in + (size_t)b * DS + cn);
    const float4 wv = *(const float4*)(lnw + cn);
    const float4 bv = *(const float4*)(lnb + cn);
    float4 o;
    o.x = (xv.x - mu) * rs * wv.x + bv.x;
    o.y = (xv.y - mu) * rs * wv.y + bv.y;
    o.z = (xv.z - mu) * rs * wv.z + bv.z;
    o.w = (xv.w - mu) * rs * wv.w + bv.w;
    *(float4*)(out + (size_t)b * DS + cn) = o;
}

// ---------- fused LN1-apply + MLP + residual + LN2 stats, 128-col tile ----------
// Round 5: hT rows are wave-private (write rows wave*32..wave*32+31, read the
// same band), so no cross-wave hazard exists inside the os loop. Both in-loop
// barriers removed; waves pipeline independently. Only the staging barrier
// (cross-wave column split of xT) remains.
__global__ __launch_bounds__(256, 2) void k_mlp(float* __restrict__ xio,
                                                const ushort* __restrict__ w1b,
                                                const float* __restrict__ b1v,
                                                const ushort* __restrict__ w2b,
                                                const float* __restrict__ b2v,
                                                const float* __restrict__ lnw,
                                                const float* __restrict__ lnb,
                                                float* __restrict__ st) {
    __shared__ ushort xT[128 * 128];   // swizzled, x1 = LN1(x1pre) bf16
    __shared__ ushort hT[128 * 128];   // swizzled, gelu slice bf16 (wave-private rows)
    const int b = blockIdx.y;
    const int n0 = blockIdx.x * 128;
    const int t = threadIdx.x;
    const float mu = st[16 + b], rs = st[24 + b];
    {
        const int nn = t & 127, cg = t >> 7;
        const float* xp = xio + (size_t)b * DS + n0 + nn;
        const float* wp = lnw + n0 + nn;
        const float* bp = lnb + n0 + nn;
#pragma unroll
        for (int g = 0; g < 16; ++g) {
            int c0 = cg * 64 + g * 4;
            ushort4 pk;
            pk.x = f2b(fmaf((xp[(size_t)(c0 + 0) * N_SP] - mu) * rs,
                            wp[(size_t)(c0 + 0) * N_SP], bp[(size_t)(c0 + 0) * N_SP]));
            pk.y = f2b(fmaf((xp[(size_t)(c0 + 1) * N_SP] - mu) * rs,
                            wp[(size_t)(c0 + 1) * N_SP], bp[(size_t)(c0 + 1) * N_SP]));
            pk.z = f2b(fmaf((xp[(size_t)(c0 + 2) * N_SP] - mu) * rs,
                            wp[(size_t)(c0 + 2) * N_SP], bp[(size_t)(c0 + 2) * N_SP]));
            pk.w = f2b(fmaf((xp[(size_t)(c0 + 3) * N_SP] - mu) * rs,
                            wp[(size_t)(c0 + 3) * N_SP], bp[(size_t)(c0 + 3) * N_SP]));
            *(ushort4*)&xT[swz4(nn, c0)] = pk;
        }
    }
    __syncthreads();   // the ONLY barrier: xT columns are staged by paired waves
    const int wave = t >> 6, lane = t & 63, q = lane >> 4, r = lane & 15;
    const int nr0 = wave * 32 + r, nr1 = nr0 + 16;
    f4 acc2[8][2];
#pragma unroll
    for (int m = 0; m < 8; ++m) { acc2[m][0] = (f4){0,0,0,0}; acc2[m][1] = (f4){0,0,0,0}; }

    for (int os = 0; os < 4; ++os) {
        f4 acc1[8][2];
#pragma unroll
        for (int m = 0; m < 8; ++m) { acc1[m][0] = (f4){0,0,0,0}; acc1[m][1] = (f4){0,0,0,0}; }
#pragma unroll
        for (int kk = 0; kk < 4; ++kk) {
            const int c0 = kk * 32 + q * 8;
            s8b b0 = *(const s8b*)&xT[swz8(nr0, c0)];
            s8b b1 = *(const s8b*)&xT[swz8(nr1, c0)];
#pragma unroll
            for (int m = 0; m < 8; ++m) {
                s8b a = *(const s8b*)(w1b + (size_t)(os * 128 + m * 16 + r) * 128 + c0);
                acc1[m][0] = __builtin_amdgcn_mfma_f32_16x16x32_bf16(a, b0, acc1[m][0], 0, 0, 0);
                acc1[m][1] = __builtin_amdgcn_mfma_f32_16x16x32_bf16(a, b1, acc1[m][1], 0, 0, 0);
            }
        }
        // no barrier: hT rows [wave*32, wave*32+32) are written and read only
        // by this wave; same-wave DS ops complete in order.
#pragma unroll
        for (int n2 = 0; n2 < 2; ++n2) {
            const int nr = wave * 32 + n2 * 16 + r;
#pragma unroll
            for (int m = 0; m < 8; ++m) {
                const int o0 = m * 16 + q * 4;
                ushort4 pk;
                pk.x = f2b(gelu_f(acc1[m][n2][0] + b1v[os * 128 + o0 + 0]));
                pk.y = f2b(gelu_f(acc1[m][n2][1] + b1v[os * 128 + o0 + 1]));
                pk.z = f2b(gelu_f(acc1[m][n2][2] + b1v[os * 128 + o0 + 2]));
                pk.w = f2b(gelu_f(acc1[m][n2][3] + b1v[os * 128 + o0 + 3]));
                *(ushort4*)&hT[swz4(nr, o0)] = pk;
            }
        }
        // no barrier (same reasoning)
#pragma unroll
        for (int kk = 0; kk < 4; ++kk) {
            const int c0 = kk * 32 + q * 8;
            s8b h0 = *(const s8b*)&hT[swz8(nr0, c0)];
            s8b h1 = *(const s8b*)&hT[swz8(nr1, c0)];
#pragma unroll
            for (int m = 0; m < 8; ++m) {
                s8b a = *(const s8b*)(w2b + (size_t)(m * 16 + r) * 512 + os * 128 + c0);
                acc2[m][0] = __builtin_amdgcn_mfma_f32_16x16x32_bf16(a, h0, acc2[m][0], 0, 0, 0);
                acc2[m][1] = __builtin_amdgcn_mfma_f32_16x16x32_bf16(a, h1, acc2[m][1], 0, 0, 0);
            }
        }
    }
    float s = 0.f, sq = 0.f;
#pragma unroll
    for (int n2 = 0; n2 < 2; ++n2) {
        const int nrl = wave * 32 + n2 * 16 + r;
        float* op = xio + (size_t)b * DS + n0 + nrl;
#pragma unroll
        for (int m = 0; m < 8; ++m) {
            const int o0 = m * 16 + q * 4;
            ushort4 xr = *(const ushort4*)&xT[swz4(nrl, o0)];
            float v0 = acc2[m][n2][0] + b2v[o0 + 0] + b2f(xr.x);
            float v1 = acc2[m][n2][1] + b2v[o0 + 1] + b2f(xr.y);
            float v2 = acc2[m][n2][2] + b2v[o0 + 2] + b2f(xr.z);
            float v3 = acc2[m][n2][3] + b2v[o0 + 3] + b2f(xr.w);
            op[(size_t)(o0 + 0) * N_SP] = v0;
            op[(size_t)(o0 + 1) * N_SP] = v1;
            op[(size_t)(o0 + 2) * N_SP] = v2;
            op[(size_t)(o0 + 3) * N_SP] = v3;
            s += (v0 + v1) + (v2 + v3);
            sq = fmaf(v0, v0, sq); sq = fmaf(v1, v1, sq);
            sq = fmaf(v2, v2, sq); sq = fmaf(v3, v3, sq);
        }
    }
#pragma unroll
    for (int off = 32; off > 0; off >>= 1) {
        s += __shfl_down(s, off, 64);
        sq += __shfl_down(sq, off, 64);
    }
    if (lane == 0) {
        atomicAdd(&st[32 + b], s);
        atomicAdd(&st[40 + b], sq);
    }
}

extern "C" void kernel_launch(void* const* d_in, const int* in_sizes, int n_in,
                              void* d_out, int out_size, void* d_ws, size_t ws_size,
                              hipStream_t stream) {
    const float* x      = (const float*)d_in[0];
    const float* qkv_w  = (const float*)d_in[1];
    const float* proj_w = (const float*)d_in[2];
    const float* proj_b = (const float*)d_in[3];
    const float* ln1_w  = (const float*)d_in[4];
    const float* ln1_b  = (const float*)d_in[5];
    const float* ln2_w  = (const float*)d_in[6];
    const float* ln2_b  = (const float*)d_in[7];
    const float* mlp_w1 = (const float*)d_in[8];
    const float* mlp_b1 = (const float*)d_in[9];
    const float* mlp_w2 = (const float*)d_in[10];
    const float* mlp_b2 = (const float*)d_in[11];
    float* out = (float*)d_out;

    char* wsb = (char*)d_ws;
    float*  Gpart = (float*)wsb;                      // 33,554,432 B
    float*  G     = (float*)(wsb + 33554432);         // 524,288
    float*  attn  = (float*)(wsb + 34078720);         // 65,536
    float*  PT    = (float*)(wsb + 34144256);         // 65,536
    float*  st    = (float*)(wsb + 34209792);         // 256
    ushort* Mbb   = (ushort*)(wsb + 34210048);        // 262,144
    ushort* w1b   = (ushort*)(wsb + 34472192);        // 131,072
    ushort* w2b   = (ushort*)(wsb + 34603264);        // 131,072

    hipMemsetAsync(st, 0, 64 * sizeof(float), stream);

    k_transpose<<<64, 256, 0, stream>>>(proj_w, PT, 128, 128);
    k_cvt<<<256, 256, 0, stream>>>(mlp_w1, w1b, 65536);
    k_cvt<<<256, 256, 0, stream>>>(mlp_w2, w2b, 65536);

    k_cov<<<dim3(64, 8), 256, 0, stream>>>(x, Gpart);
    k_greduce<<<512, 256, 0, stream>>>(Gpart, G);
    k_gram_small<<<64, 256, 0, stream>>>(G, qkv_w, attn);
    k_mfold<<<8, 256, 0, stream>>>(attn, qkv_w, PT, Mbb);

    k_attnproj<<<dim3(256, 8), 256, 0, stream>>>(x, Mbb, proj_b, out, st);
    k_finalize<<<1, 64, 0, stream>>>(st, 0);
    // LN1 apply fused into k_mlp staging
    k_mlp<<<dim3(256, 8), 256, 0, stream>>>(out, w1b, mlp_b1, w2b, mlp_b2,
                                            ln1_w, ln1_b, st);
    k_finalize<<<1, 64, 0, stream>>>(st, 32);
    k_lnapply<<<32768, 256, 0, stream>>>(out, ln2_w, ln2_b, st, 32, out);
}